// Round 2
// baseline (9129.033 us; speedup 1.0000x reference)
//
#include <hip/hip_runtime.h>

typedef unsigned short u16;
typedef unsigned int   u32;
typedef unsigned long long u64;
typedef __attribute__((ext_vector_type(8))) short  short8;
typedef __attribute__((ext_vector_type(4))) float  floatx4;

__device__ __forceinline__ u16 f2bf(float f){
  u32 x = __float_as_uint(f);
  x += 0x7fffu + ((x >> 16) & 1u);   // round-to-nearest-even
  return (u16)(x >> 16);
}
__device__ __forceinline__ u32 pk(float a, float b){
  return (u32)f2bf(a) | ((u32)f2bf(b) << 16);
}

// ---------------------------------------------------------------------------
// GEMM: C[M][N](f32) = A[M][K] @ B[N][K](f32)^T + bias1[N] (+ bias2[N]).
// A is f32 (a_f32=1, optional row indirection) or bf16 (a_f32=0).
// f32 operands are rounded to bf16 during LDS staging; MFMA bf16 compute.
// 128x128 tile, BK=32, 4 waves (2x2 of 64x64), mfma_f32_16x16x32_bf16.
// A-frag: A[m=lane&15][k=quad*8+j]; D: row=quad*4+r, col=lane&15 (m89/m91).
// ---------------------------------------------------------------------------
#define TM 128
#define TN 128
#define BK 32
#define LDK 40   // +8 bf16 pad: keeps 16B alignment, breaks bank patterns

__global__ __launch_bounds__(256) void k_gemm(
    const void* __restrict__ Av, int a_f32, const int* __restrict__ a_rows,
    const float* __restrict__ B,
    const float* __restrict__ bias1, const float* __restrict__ bias2,
    float* __restrict__ outC,
    int M, int N, int K)
{
  __shared__ u16 As[TM][LDK];
  __shared__ u16 Bs[TN][LDK];
  const int tid  = threadIdx.x;
  const int n0   = blockIdx.x * TN;
  const int m0   = blockIdx.y * TM;
  const int wave = tid >> 6;
  const int lane = tid & 63;
  const int quad = lane >> 4;
  const int l16  = lane & 15;
  const int wm   = (wave >> 1) * 64;
  const int wn   = (wave & 1) * 64;

  // staging: thread -> (row, 16-elem half of the BK=32 slab)
  const int srow = tid >> 1;
  const int scol = (tid & 1) * 16;
  int am = m0 + srow;
  if (a_rows) am = a_rows[am];
  const float* apf = (const float*)Av + (long)am * K + scol;
  const u16*   aph = (const u16*)Av + (long)am * K + scol;
  const float* bpf = B + (long)(n0 + srow) * K + scol;

  floatx4 acc[4][4] = {};

  for (int k0 = 0; k0 < K; k0 += BK){
    // B: 16 f32 -> 16 bf16
    float4 b0 = *(const float4*)(bpf + k0);
    float4 b1 = *(const float4*)(bpf + k0 + 4);
    float4 b2 = *(const float4*)(bpf + k0 + 8);
    float4 b3 = *(const float4*)(bpf + k0 + 12);
    uint4 aS0, aS1;
    if (a_f32){
      float4 a0 = *(const float4*)(apf + k0);
      float4 a1 = *(const float4*)(apf + k0 + 4);
      float4 a2 = *(const float4*)(apf + k0 + 8);
      float4 a3 = *(const float4*)(apf + k0 + 12);
      aS0 = make_uint4(pk(a0.x,a0.y), pk(a0.z,a0.w), pk(a1.x,a1.y), pk(a1.z,a1.w));
      aS1 = make_uint4(pk(a2.x,a2.y), pk(a2.z,a2.w), pk(a3.x,a3.y), pk(a3.z,a3.w));
    } else {
      aS0 = *(const uint4*)(aph + k0);
      aS1 = *(const uint4*)(aph + k0 + 8);
    }
    uint4 bS0 = make_uint4(pk(b0.x,b0.y), pk(b0.z,b0.w), pk(b1.x,b1.y), pk(b1.z,b1.w));
    uint4 bS1 = make_uint4(pk(b2.x,b2.y), pk(b2.z,b2.w), pk(b3.x,b3.y), pk(b3.z,b3.w));
    __syncthreads();
    *(uint4*)&As[srow][scol]     = aS0;
    *(uint4*)&As[srow][scol + 8] = aS1;
    *(uint4*)&Bs[srow][scol]     = bS0;
    *(uint4*)&Bs[srow][scol + 8] = bS1;
    __syncthreads();
    short8 af[4], bfg[4];
    #pragma unroll
    for (int mt = 0; mt < 4; mt++) af[mt]  = *(const short8*)&As[wm + mt*16 + l16][quad*8];
    #pragma unroll
    for (int nt = 0; nt < 4; nt++) bfg[nt] = *(const short8*)&Bs[wn + nt*16 + l16][quad*8];
    #pragma unroll
    for (int mt = 0; mt < 4; mt++)
      #pragma unroll
      for (int nt = 0; nt < 4; nt++)
        acc[mt][nt] = __builtin_amdgcn_mfma_f32_16x16x32_bf16(af[mt], bfg[nt], acc[mt][nt], 0, 0, 0);
  }

  #pragma unroll
  for (int nt = 0; nt < 4; nt++){
    const int col = n0 + wn + nt*16 + l16;
    float bias = bias1[col];
    if (bias2) bias += bias2[col];
    #pragma unroll
    for (int mt = 0; mt < 4; mt++){
      #pragma unroll
      for (int r = 0; r < 4; r++){
        const int row = m0 + wm + mt*16 + quad*4 + r;
        outC[(long)row * N + col] = acc[mt][nt][r] + bias;
      }
    }
  }
}

// ---------------------------------------------------------------------------
// LSTM scan, one layer. 256 WGs = (8 batch) x (32 chunks of 16 hidden units),
// grid == CU count so all WGs are co-resident (1 WG/CU fits trivially:
// ~2.4 KB LDS, <256 VGPR). W_hh slice (64 rows x 512 f32) register-resident
// (128 VGPR/thread). h exchanged through LLC with agent-scope atomics;
// per-batch monotonic-counter barrier (32 arrivals/step); h double-buffered
// on t-parity so step t+1 writes never race step t reads.
// ---------------------------------------------------------------------------
__global__ __launch_bounds__(256, 1) void k_scan(
    const float* __restrict__ xg,    // [4096][2048] f32, m = b*512 + t
    const float* __restrict__ Whh,   // [2048][512] f32
    u16*        __restrict__ h_hist, // [4096][512] bf16 out
    float*      __restrict__ hbuf,   // [2][8][512] f32 (LLC exchange)
    int*        __restrict__ cnt)    // per-batch counters, stride 32 ints
{
  const int tid   = threadIdx.x;
  const int b     = blockIdx.x & 7;
  const int chunk = blockIdx.x >> 3;   // 0..31
  const int c0    = chunk * 16;
  const int rr    = tid >> 2;          // 0..63 : local gate-row
  const int g     = rr >> 4;           // 0..3  : i,f,g,o
  const int jj    = rr & 15;           // hidden unit within chunk
  const int p     = tid & 3;           // K-quarter
  const int nrow  = g * 512 + c0 + jj; // global gate row in [0,2048)

  __shared__ __align__(16) float h_lds[512];
  __shared__ float gates[64];
  __shared__ float c_lds[16];
  if (tid < 16) c_lds[tid] = 0.f;

  // W_hh[nrow][p*128 .. p*128+127] -> 32 float4 (128 VGPRs)
  float4 w[32];
  const float4* wgp = (const float4*)(Whh + (long)nrow * 512 + p * 128);
  #pragma unroll
  for (int i = 0; i < 32; i++) w[i] = wgp[i];

  int* cnt_b = cnt + b * 32;
  const long xgbase = (long)b * 512 * 2048;
  int target = 0;

  for (int t = 0; t < 512; t++){
    float xgv = 0.f;
    if (p == 0) xgv = xg[xgbase + (long)t * 2048 + nrow];  // no h dependency
    if (t > 0){
      const u64* hsrc = (const u64*)(hbuf + (((t - 1) & 1) * 8 + b) * 512);
      u64 v = __hip_atomic_load(hsrc + tid, __ATOMIC_RELAXED, __HIP_MEMORY_SCOPE_AGENT);
      ((u64*)h_lds)[tid] = v;
    }
    __syncthreads();

    float s = 0.f;
    if (t > 0){
      const float* hp = h_lds + p * 128;
      #pragma unroll
      for (int i = 0; i < 32; i++){
        float4 h4 = *(const float4*)(hp + i * 4);
        s += w[i].x * h4.x + w[i].y * h4.y + w[i].z * h4.z + w[i].w * h4.w;
      }
    }
    s += __shfl_xor(s, 1);
    s += __shfl_xor(s, 2);

    if (p == 0){
      float gv = xgv + s;
      gv = (g == 2) ? tanhf(gv) : 1.f / (1.f + __expf(-gv));
      gates[rr] = gv;
    }
    __syncthreads();

    if (tid < 16){   // wave 0; __syncthreads drains these stores before arrive
      float iv = gates[tid], fv = gates[16 + tid], gg = gates[32 + tid], ov = gates[48 + tid];
      float c = fv * c_lds[tid] + iv * gg;
      c_lds[tid] = c;
      float h = ov * tanhf(c);
      __hip_atomic_store(hbuf + ((t & 1) * 8 + b) * 512 + c0 + tid, h,
                         __ATOMIC_RELAXED, __HIP_MEMORY_SCOPE_AGENT);
      h_hist[(long)(b * 512 + t) * 512 + c0 + tid] = f2bf(h);
    }
    __syncthreads();

    target += 32;
    if (tid == 0){
      __hip_atomic_fetch_add(cnt_b, 1, __ATOMIC_RELEASE, __HIP_MEMORY_SCOPE_AGENT);
      while (__hip_atomic_load(cnt_b, __ATOMIC_ACQUIRE, __HIP_MEMORY_SCOPE_AGENT) < target){
        __builtin_amdgcn_s_sleep(1);
      }
    }
    __syncthreads();
  }
}

__global__ void k_init(int* cnt){ cnt[threadIdx.x] = 0; }

// ---------------------------------------------------------------------------
extern "C" void kernel_launch(void* const* d_in, const int* in_sizes, int n_in,
                              void* d_out, int out_size, void* d_ws, size_t ws_size,
                              hipStream_t stream)
{
  const int*   ids  = (const int*)d_in[0];
  const float* emb  = (const float*)d_in[1];
  const float* Wih0 = (const float*)d_in[2];
  const float* Whh0 = (const float*)d_in[3];
  const float* bih0 = (const float*)d_in[4];
  const float* bhh0 = (const float*)d_in[5];
  const float* Wih1 = (const float*)d_in[6];
  const float* Whh1 = (const float*)d_in[7];
  const float* bih1 = (const float*)d_in[8];
  const float* bhh1 = (const float*)d_in[9];
  const float* Wfc  = (const float*)d_in[10];
  const float* bfc  = (const float*)d_in[11];
  float* out = (float*)d_out;

  char* ws = (char*)d_ws;
  float* xg   = (float*)(ws);                            // 33,554,432 B
  u16*   h0   = (u16*) (ws + (size_t)33554432);          //  4,194,304 B
  u16*   h1   = (u16*) (ws + (size_t)37748736);          //  4,194,304 B
  float* hbuf = (float*)(ws + (size_t)41943040);         //     32,768 B
  int*   cnt  = (int*)  (ws + (size_t)41943040 + 32768); //      4,096 B

  k_init<<<dim3(1), dim3(1024), 0, stream>>>(cnt);

  // xg0 = emb[ids] @ W_ih0^T + b_ih0 + b_hh0   (K=256, A=f32+indirect)
  k_gemm<<<dim3(16, 32), dim3(256), 0, stream>>>(
      (const void*)emb, 1, ids, Wih0, bih0, bhh0, xg, 4096, 2048, 256);

  k_scan<<<dim3(256), dim3(256), 0, stream>>>(xg, Whh0, h0, hbuf, cnt);

  // xg1 = h0 @ W_ih1^T + b_ih1 + b_hh1   (K=512, A=bf16)
  k_gemm<<<dim3(16, 32), dim3(256), 0, stream>>>(
      (const void*)h0, 0, (const int*)nullptr, Wih1, bih1, bhh1, xg, 4096, 2048, 512);

  k_scan<<<dim3(256), dim3(256), 0, stream>>>(xg, Whh1, h1, hbuf, cnt + 256);

  // logits = h1 @ W_fc^T + b_fc -> f32 d_out   (N=32000, A=bf16)
  k_gemm<<<dim3(250, 32), dim3(256), 0, stream>>>(
      (const void*)h1, 0, (const int*)nullptr, Wfc, bfc, (const float*)nullptr,
      out, 4096, 32000, 512);
}